// Round 11
// baseline (235.589 us; speedup 1.0000x reference)
//
#include <hip/hip_runtime.h>
#include <math.h>

constexpr int KK = 2;
constexpr int HH = 4;
constexpr int NN = 4096;
constexpr int DD = 64;
constexpr int OO = 64;
constexpr int NU = 4000;
constexpr int CC = 2;
constexpr float LOG2E = 1.44269504088896340736f;

typedef float vf4 __attribute__((ext_vector_type(4)));
typedef float vf2 __attribute__((ext_vector_type(2)));

__device__ __forceinline__ float fexp2(float x) {
#if __has_builtin(__builtin_amdgcn_exp2f)
  return __builtin_amdgcn_exp2f(x);
#else
  return exp2f(x);
#endif
}
__device__ __forceinline__ float frcp(float x) {
#if __has_builtin(__builtin_amdgcn_rcpf)
  return __builtin_amdgcn_rcpf(x);
#else
  return 1.0f / x;
#endif
}
__device__ __forceinline__ float ftanh(float x) {
  float e = fexp2(x * (2.0f * LOG2E));
  return 1.0f - 2.0f * frcp(e + 1.0f);
}

// ---------------------------------------------------------------------------
// Phase 1: per (k,h): hp = h @ w; per node (SoA planes, factorized):
//   srcAA[kh][i] = {2^src', 2^(0.2 src')}
//   Bp[kh][j]=2^dst', B5p[kh][j]=2^(0.2 dst'), g0p/g1p[kh][j]=hp_j.fc_w_c
// exp2(leaky(s)) == max(A*B, A5*B5)  (exact; validated R9/R10).
// grid (128, K*H), block 256, 32 rows/block; thread = 2 rows x 4 o.
// LDS: w 16 KB + union(h_s 9 KB | part 8.5 KB) = 25.6 KB -> 6 blocks/CU.
// ---------------------------------------------------------------------------
__global__ __launch_bounds__(256) void gat_phase1(
    const float* __restrict__ hsrc, const float* __restrict__ w,
    const float* __restrict__ a_src, const float* __restrict__ a_dst,
    const float* __restrict__ fc_w,
    float* __restrict__ srcAA, float* __restrict__ Bp,
    float* __restrict__ B5p, float* __restrict__ g0p,
    float* __restrict__ g1p) {
  const int kh = blockIdx.y;  // 0..7
  const int k = kh >> 2;
  const int i0 = blockIdx.x * 32;
  const int tid = threadIdx.x;

  __shared__ float w_s[DD][OO];
  __shared__ float hs_un[DD * 36];  // h_s[f][row(+pad)] | later part[4][32][17]

  {
    const vf4* wp = (const vf4*)(w + (size_t)kh * DD * OO);
    vf4* ws4 = (vf4*)w_s;
    for (int t = tid; t < DD * OO / 4; t += 256) ws4[t] = wp[t];
  }
  for (int t = tid; t < 512; t += 256) {  // 32 rows x 16 vf4
    const int row = t >> 4;
    const int f4 = (t & 15) * 4;
    vf4 v = *(const vf4*)(hsrc + (size_t)(i0 + row) * DD + f4);
    hs_un[(f4 + 0) * 36 + row] = v.x;
    hs_un[(f4 + 1) * 36 + row] = v.y;
    hs_un[(f4 + 2) * 36 + row] = v.z;
    hs_un[(f4 + 3) * 36 + row] = v.w;
  }
  __syncthreads();

  const int og = tid & 15;  // o0 = og*4
  const int rg = tid >> 4;  // rows r0, r0+1
  const int o0 = og * 4;
  const int r0 = rg * 2;

  float hp[2][4];
#pragma unroll
  for (int j = 0; j < 2; ++j)
#pragma unroll
    for (int u = 0; u < 4; ++u) hp[j][u] = 0.0f;

#pragma unroll 8
  for (int f = 0; f < DD; ++f) {
    vf2 hv = *(const vf2*)&hs_un[f * 36 + r0];
    vf4 wv = *(const vf4*)&w_s[f][o0];
    hp[0][0] = fmaf(hv.x, wv.x, hp[0][0]);
    hp[0][1] = fmaf(hv.x, wv.y, hp[0][1]);
    hp[0][2] = fmaf(hv.x, wv.z, hp[0][2]);
    hp[0][3] = fmaf(hv.x, wv.w, hp[0][3]);
    hp[1][0] = fmaf(hv.y, wv.x, hp[1][0]);
    hp[1][1] = fmaf(hv.y, wv.y, hp[1][1]);
    hp[1][2] = fmaf(hv.y, wv.z, hp[1][2]);
    hp[1][3] = fmaf(hv.y, wv.w, hp[1][3]);
  }

  float as[4], ad[4], f0[4], f1[4];
#pragma unroll
  for (int u = 0; u < 4; ++u) {
    as[u] = a_src[kh * OO + o0 + u];
    ad[u] = a_dst[kh * OO + o0 + u];
    f0[u] = fc_w[0 * (KK * OO) + k * OO + o0 + u];
    f1[u] = fc_w[1 * (KK * OO) + k * OO + o0 + u];
  }

  float vals[2][4];  // [row][{sp,dp,g0,g1}] partial over this og's 4 o
#pragma unroll
  for (int j = 0; j < 2; ++j) {
    float sp = 0.0f, dp = 0.0f, g0 = 0.0f, g1 = 0.0f;
#pragma unroll
    for (int u = 0; u < 4; ++u) {
      float v = hp[j][u];
      float t = ftanh(v);
      sp = fmaf(t, as[u], sp);
      dp = fmaf(t, ad[u], dp);
      g0 = fmaf(v, f0[u], g0);
      g1 = fmaf(v, f1[u], g1);
    }
    vals[j][0] = sp;
    vals[j][1] = dp;
    vals[j][2] = g0;
    vals[j][3] = g1;
  }
  __syncthreads();  // all h_s reads done -> reuse union as part[]

  // part[val][row][og] = hs_un[(val*32+row)*17+og]
#pragma unroll
  for (int j = 0; j < 2; ++j) {
#pragma unroll
    for (int v = 0; v < 4; ++v)
      hs_un[(v * 32 + r0 + j) * 17 + og] = vals[j][v];
  }
  __syncthreads();

  if (tid < 128) {  // thread = (row j2, val): sum 16 og-partials, write out
    const int val = tid & 3;
    const int j2 = tid >> 2;
    const float* pr = &hs_un[(val * 32 + j2) * 17];
    vf4 s0 = *(const vf4*)(pr + 0);
    vf4 s1 = *(const vf4*)(pr + 4);
    vf4 s2 = *(const vf4*)(pr + 8);
    vf4 s3 = *(const vf4*)(pr + 12);
    vf4 t4 = s0 + s1 + s2 + s3;
    float sum = t4.x + t4.y + t4.z + t4.w;
    const size_t idx = (size_t)kh * NN + i0 + j2;
    if (val == 0) {
      float sp = sum * LOG2E;
      vf2 v = {fexp2(sp), fexp2(0.2f * sp)};
      *(vf2*)(srcAA + idx * 2) = v;
    } else if (val == 1) {
      float dp = sum * LOG2E;
      Bp[idx] = fexp2(dp);
      B5p[idx] = fexp2(0.2f * dp);
    } else if (val == 2) {
      g0p[idx] = sum;
    } else {
      g1p[idx] = sum;
    }
  }
}

// ---------------------------------------------------------------------------
// Phase 2: grid (NU/4, K), block 256 = 4 waves, 4 rows/block, lane = j.
// Wave w owns j in [w*1024, (w+1)*1024), 4 tiles of 256 j. All loads dense
// vf4 (1 KB/instr). Software pipeline: next-tile adj prefetched before
// current compute; next-h planes double-buffered. Scalar accumulators
// (48 VGPR) keep the live set small.
//   e = max(A*B, A5*B5); l += e*adj; a_c += (e*adj)*g_c
// Reduce: butterfly(48) + LDS combine + divide -> S[k][i][c].
// ---------------------------------------------------------------------------
__global__ __launch_bounds__(256) void gat_phase2(
    const float* __restrict__ adj, const float* __restrict__ srcAA,
    const float* __restrict__ Bp, const float* __restrict__ B5p,
    const float* __restrict__ g0p, const float* __restrict__ g1p,
    float* __restrict__ S) {
  const int k = blockIdx.y;
  const int r0 = blockIdx.x * 4;
  const int tid = threadIdx.x;
  const int wave = tid >> 6;
  const int lane = tid & 63;

  // wave-uniform A factors (scalar loads)
  float A[4][4], A5[4][4];  // [r][h]
#pragma unroll
  for (int h = 0; h < 4; ++h) {
    const float* base = srcAA + ((size_t)(k * HH + h) * NN + r0) * 2;
#pragma unroll
    for (int r = 0; r < 4; ++r) {
      A[r][h] = base[r * 2 + 0];
      A5[r][h] = base[r * 2 + 1];
    }
  }

  float l[4][4], a0[4][4], a1[4][4];  // [r][h] scalar accumulators
#pragma unroll
  for (int r = 0; r < 4; ++r)
#pragma unroll
    for (int h = 0; h < 4; ++h) {
      l[r][h] = 0.0f;
      a0[r][h] = 0.0f;
      a1[r][h] = 0.0f;
    }

  const float* adjk = adj + (size_t)k * NN * NN;
  const int jw = wave * 1024 + lane * 4;

  vf4 avc[4], avn[4];
#pragma unroll
  for (int r = 0; r < 4; ++r)
    avc[r] = *(const vf4*)(adjk + (size_t)(r0 + r) * NN + jw);

#pragma unroll 1
  for (int t = 0; t < 4; ++t) {
    const int j = jw + t * 256;
    if (t < 3) {  // prefetch next tile's adj (covers HBM/L3 latency)
#pragma unroll
      for (int r = 0; r < 4; ++r)
        avn[r] = *(const vf4*)(adjk + (size_t)(r0 + r) * NN + j + 256);
    }
    // plane double-buffer over h
    size_t pb = (size_t)(k * HH + 0) * NN + j;
    vf4 bC = *(const vf4*)(Bp + pb);
    vf4 b5C = *(const vf4*)(B5p + pb);
    vf4 g0C = *(const vf4*)(g0p + pb);
    vf4 g1C = *(const vf4*)(g1p + pb);
#pragma unroll
    for (int h = 0; h < 4; ++h) {
      vf4 b = bC, b5 = b5C, g0 = g0C, g1 = g1C;
      if (h < 3) {
        size_t pn = (size_t)(k * HH + h + 1) * NN + j;
        bC = *(const vf4*)(Bp + pn);
        b5C = *(const vf4*)(B5p + pn);
        g0C = *(const vf4*)(g0p + pn);
        g1C = *(const vf4*)(g1p + pn);
      }
      vf2 blo = {b.x, b.y}, bhi = {b.z, b.w};
      vf2 b5lo = {b5.x, b5.y}, b5hi = {b5.z, b5.w};
#pragma unroll
      for (int r = 0; r < 4; ++r) {
        vf2 elo = __builtin_elementwise_max(blo * A[r][h], b5lo * A5[r][h]);
        vf2 ehi = __builtin_elementwise_max(bhi * A[r][h], b5hi * A5[r][h]);
        float p0 = elo.x * avc[r].x;
        float p1 = elo.y * avc[r].y;
        float p2 = ehi.x * avc[r].z;
        float p3 = ehi.y * avc[r].w;
        l[r][h] += (p0 + p1) + (p2 + p3);
        a0[r][h] = fmaf(p0, g0.x, fmaf(p1, g0.y, fmaf(p2, g0.z, fmaf(p3, g0.w, a0[r][h]))));
        a1[r][h] = fmaf(p0, g1.x, fmaf(p1, g1.y, fmaf(p2, g1.z, fmaf(p3, g1.w, a1[r][h]))));
      }
    }
#pragma unroll
    for (int r = 0; r < 4; ++r) avc[r] = avn[r];
  }

  // butterfly across 64 lanes (48 scalars)
  float red[4][4][3];
#pragma unroll
  for (int r = 0; r < 4; ++r)
#pragma unroll
    for (int h = 0; h < 4; ++h) {
      float x0 = l[r][h], x1 = a0[r][h], x2 = a1[r][h];
#pragma unroll
      for (int off = 32; off > 0; off >>= 1) {
        x0 += __shfl_xor(x0, off, 64);
        x1 += __shfl_xor(x1, off, 64);
        x2 += __shfl_xor(x2, off, 64);
      }
      red[r][h][0] = x0;
      red[r][h][1] = x1;
      red[r][h][2] = x2;
    }

  __shared__ float sred[4][48];
  if (lane == 0) {
#pragma unroll
    for (int r = 0; r < 4; ++r)
#pragma unroll
      for (int h = 0; h < 4; ++h) {
#pragma unroll
        for (int c = 0; c < 3; ++c)
          sred[wave][(r * 4 + h) * 3 + c] = red[r][h][c];
      }
  }
  __syncthreads();
  if (tid < 8) {
    const int r = tid >> 1, c = tid & 1;
    float acc = 0.0f;
#pragma unroll
    for (int h = 0; h < 4; ++h) {
      const int vb = (r * 4 + h) * 3;
      float ls = sred[0][vb] + sred[1][vb] + sred[2][vb] + sred[3][vb];
      float ac = sred[0][vb + 1 + c] + sred[1][vb + 1 + c] +
                 sred[2][vb + 1 + c] + sred[3][vb + 1 + c];
      acc += ac / ls;
    }
    S[((size_t)k * NU + r0 + r) * CC + c] = 0.25f * acc;
  }
}

// ---------------------------------------------------------------------------
// Phase 3: sum kinds, +bias, log_softmax over C=2.
// ---------------------------------------------------------------------------
__global__ __launch_bounds__(256) void gat_phase3(
    const float* __restrict__ S, const float* __restrict__ fc_b,
    float* __restrict__ out) {
  const int i = blockIdx.x * 256 + threadIdx.x;
  if (i >= NU) return;
  float l0 = S[(size_t)i * CC + 0] + S[((size_t)NU + i) * CC + 0] + fc_b[0];
  float l1 = S[(size_t)i * CC + 1] + S[((size_t)NU + i) * CC + 1] + fc_b[1];
  float m = fmaxf(l0, l1);
  float lse = m + logf(expf(l0 - m) + expf(l1 - m));
  out[i * CC + 0] = l0 - lse;
  out[i * CC + 1] = l1 - lse;
}

extern "C" void kernel_launch(void* const* d_in, const int* in_sizes, int n_in,
                              void* d_out, int out_size, void* d_ws, size_t ws_size,
                              hipStream_t stream) {
  const float* hsrc  = (const float*)d_in[0];  // (1,4096,64)
  const float* hadj  = (const float*)d_in[1];  // (2,1,4096,4096)
  const float* w     = (const float*)d_in[2];  // (2,4,64,64)
  const float* a_src = (const float*)d_in[3];  // (2,4,64,1)
  const float* a_dst = (const float*)d_in[4];  // (2,4,64,1)
  const float* fc_w  = (const float*)d_in[5];  // (2,128)
  const float* fc_b  = (const float*)d_in[6];  // (2,)
  float* out = (float*)d_out;                  // (1,4000,2) fp32

  char* ws = (char*)d_ws;
  float* srcAA = (float*)(ws + 0);        // K*H*N*2 (256 KB)
  float* Bp    = (float*)(ws + 262144);   // K*H*N   (128 KB)
  float* B5p   = (float*)(ws + 393216);
  float* g0p   = (float*)(ws + 524288);
  float* g1p   = (float*)(ws + 655360);
  float* S     = (float*)(ws + 786432);   // K*NU*C  (64 KB)

  dim3 g1(NN / 32, KK * HH);
  gat_phase1<<<g1, 256, 0, stream>>>(hsrc, w, a_src, a_dst, fc_w,
                                     srcAA, Bp, B5p, g0p, g1p);
  dim3 g2(NU / 4, KK);
  gat_phase2<<<g2, 256, 0, stream>>>(hadj, srcAA, Bp, B5p, g0p, g1p, S);
  gat_phase3<<<(NU + 255) / 256, 256, 0, stream>>>(S, fc_b, out);
}